// Round 4
// baseline (64.676 us; speedup 1.0000x reference)
//
#include <hip/hip_runtime.h>
#include <math.h>

// Algebraic refactor (verified rounds 1-3, absmax <= 0.0039):
//  y[0]=x[...,0]; y[k]=x[...,k]+relu(Wc@y[k-1])
//  z[0]=f(y[0]);  z[k]=f(y[k])+relu(Wc@z[k-1]),  f(v)=relu(v*inv+add)
//  S[col][dh] = sum_{o,k} A[dh][24-k][o] * t2[k][o][col],  t2[k]=f(z[k])
//  tail: lerp chains + sigmoid (k3,k4)
// Round 4: serial loop made LDS-only. t2 written into the consumed x-plane
//  (b64, race-free: same-wave read-before-write + shfl data dependency);
//  S-reduction moved to a parallel post-phase (coalesced A loads).
//  Staging specialized on wave-uniform half (no division). cvt_pk packing.

#define NC 8

typedef __attribute__((ext_vector_type(8))) short bf16x8;
typedef __attribute__((ext_vector_type(4))) float f32x4;

__device__ __forceinline__ float relu_(float v) { return fmaxf(v, 0.f); }

__device__ __forceinline__ short f2bf(float f) {
  union { float f; unsigned u; } v; v.f = f;
  unsigned r = (v.u + 0x7fffu + ((v.u >> 16) & 1u)) >> 16;
  return (short)r;
}
__device__ __forceinline__ float bf2f(short s) {
  union { unsigned u; float f; } v;
  v.u = ((unsigned)(unsigned short)s) << 16;
  return v.f;
}
__device__ __forceinline__ unsigned cvtpk(float lo, float hi) {
  unsigned r;
  asm("v_cvt_pk_bf16_f32 %0, %1, %2" : "=v"(r) : "v"(lo), "v"(hi));
  return r;
}

__global__ __launch_bounds__(64) void k0_precompute(
    const float* __restrict__ Wmsg, const float* __restrict__ gamma,
    const float* __restrict__ beta, const float* __restrict__ mean,
    const float* __restrict__ var, const float* __restrict__ Wup2,
    const float* __restrict__ Wconv, const float* __restrict__ Wconv2,
    short* __restrict__ WcA, float* __restrict__ A, float* __restrict__ bnp)
{
  const int c = blockIdx.x;      // 0..255
  const int lane = threadIdx.x;  // 0..63

  // WcA[o][c] = bf16(Wc[o][c]) (MFMA A operand, row-major [M=o][K=c])
  for (int o = lane; o < 256; o += 64)
    WcA[o * 256 + c] = f2bf(Wmsg[(o * 256 + c) * 9 + 4]);

  const int gtid = c * 64 + lane;
  if (gtid < 256) {
    float inv = gamma[gtid] / sqrtf(var[gtid] + 1e-5f);
    bnp[gtid] = inv;
    bnp[256 + gtid] = beta[gtid] - mean[gtid] * inv;
  }

  float wacc[9];
#pragma unroll
  for (int q = 0; q < 9; ++q) wacc[q] = 0.f;
  for (int o = lane; o < 256; o += 64) {
    float cw = Wconv[o];
    const float* wp = Wup2 + (size_t)(o * 256 + c) * 9;
#pragma unroll
    for (int q = 0; q < 9; ++q) wacc[q] += cw * wp[q];
  }
#pragma unroll
  for (int q = 0; q < 9; ++q) {
    float v = wacc[q];
    v += __shfl_xor(v, 32, 64);
    v += __shfl_xor(v, 16, 64);
    v += __shfl_xor(v, 8, 64);
    v += __shfl_xor(v, 4, 64);
    v += __shfl_xor(v, 2, 64);
    v += __shfl_xor(v, 1, 64);
    wacc[q] = v;
  }
  if (lane == 0) {
    for (int dh = 0; dh < 3; ++dh)
      for (int j = 0; j < 25; ++j) {
        float a = 0.f;
        for (int dw = 0; dw < 3; ++dw) {
          int w = j + 1 - dw;
          if (w >= 0 && w < 25) a += wacc[dh * 3 + dw] * Wconv2[w];
        }
        A[(dh * 25 + j) * 256 + c] = a;
      }
  }
}

// ---- fused MFMA dual-recurrence kernel ----
// Block = 512 threads (8 waves). Wave w owns channels [32w, 32w+32).
// lane n=lane&15: n<8 -> y col n, n>=8 -> z col n-8 (cols = 8 consecutive h).
// xslab layout: [w][rn][c] bf16, plane w = 4096B, row rn = 512B (plain).
// After step k consumes x-plane k, z-lanes overwrite it with t2[k].
__global__ __launch_bounds__(512) void k2_fused(
    const float* __restrict__ X,     // original p2_r [b][c][h][w]
    const short* __restrict__ WcA,   // bf16 [o][c]
    const float* __restrict__ A,     // [(dh*25+w)*256+c]
    const float* __restrict__ bnp,   // inv[256], add[256]
    float* __restrict__ S)           // [col*3+dh]
{
  __shared__ short xslab[25 * 8 * 256];  // 102400B
  __shared__ short yz[2][16 * 256];      // state, swizzled (2x8192B)
  __shared__ float red[8][8][3];
  const int tid = threadIdx.x;
  const int wave = tid >> 6;
  const int lane = tid & 63;
  const int n = lane & 15;
  const int nr = n & 7;
  const int g = lane >> 4;
  const bool isz = (n >= 8);
  const int col0 = blockIdx.x * NC;      // col = b*256+h
  const int b = col0 >> 8, h0 = col0 & 255;
  const int obase = wave * 32;
  char* xs = (char*)xslab;
  char* smem = (char*)yz;

  // ---- stage x-slab (wave-uniform half -> compile-time (rn,w)) ----
  {
    auto stage = [&](int cc, const float* src, int fbase) {
#pragma unroll
      for (int j = 0; j < 25; ++j) {
        float4 v = *(const float4*)(src + j * 4);
        float vv[4] = {v.x, v.y, v.z, v.w};
#pragma unroll
        for (int e = 0; e < 4; ++e) {
          int f = fbase + j * 4 + e;  // compile-time
          int rn = f / 25, w = f - rn * 25;
          *(short*)(xs + w * 4096 + rn * 512 + 2 * cc) = f2bf(vv[e]);
        }
      }
    };
    if (tid < 256) {
      stage(tid, X + ((size_t)(b * 256 + tid) * 256 + h0) * 25, 0);
    } else {
      int c2 = tid - 256;
      stage(c2, X + ((size_t)(b * 256 + c2) * 256 + h0) * 25 + 100, 100);
    }
  }

  // BN params: o = obase + t*16 + g*4 + r
  f32x4 inv[2], addv[2];
#pragma unroll
  for (int t = 0; t < 2; ++t) {
    inv[t] = *(const f32x4*)(bnp + obase + t * 16 + g * 4);
    addv[t] = *(const f32x4*)(bnp + 256 + obase + t * 16 + g * 4);
  }

  // A-operand fragments: rows m = obase + t*16 + n, k = kk*32 + g*8 + i
  bf16x8 af[2][8];
#pragma unroll
  for (int t = 0; t < 2; ++t)
#pragma unroll
    for (int kk = 0; kk < 8; ++kk)
      af[t][kk] = *(const bf16x8*)(WcA + (obase + t * 16 + n) * 256 + kk * 32 + g * 8);

  // LDS byte offsets
  const int swz = nr << 4;
  int woff[2], roff[8], xoff[2];
#pragma unroll
  for (int t = 0; t < 2; ++t) {
    woff[t] = n * 512 + (((obase + t * 16 + g * 4) * 2) ^ swz);   // state (swizzled)
    xoff[t] = nr * 512 + 2 * (obase + t * 16 + g * 4);            // xslab (plain)
  }
#pragma unroll
  for (int kk = 0; kk < 8; ++kk)
    roff[kk] = n * 512 + ((kk * 64 + g * 16) ^ swz);

  __syncthreads();  // slab ready

  // ---- prologue (k = 0): y0 = x0, z0 = f(y0); write state + t2[0] ----
  {
    uint2 xq0[2];
#pragma unroll
    for (int t = 0; t < 2; ++t) xq0[t] = *(const uint2*)(xs + xoff[t]);
    if (!isz) {
#pragma unroll
      for (int t = 0; t < 2; ++t)
        *(uint2*)(smem + woff[t]) = xq0[t];  // y0 = x0: raw bf16 copy
    } else {
#pragma unroll
      for (int t = 0; t < 2; ++t) {
        float zr[4], t2r[4];
#pragma unroll
        for (int r = 0; r < 4; ++r) {
          short xb = (short)(r < 2 ? (r ? (xq0[t].x >> 16) : xq0[t].x)
                                   : (r & 1 ? (xq0[t].y >> 16) : xq0[t].y));
          float x = bf2f(xb);
          zr[r] = relu_(x * inv[t][r] + addv[t][r]);
          t2r[r] = relu_(zr[r] * inv[t][r] + addv[t][r]);
        }
        *(uint2*)(smem + woff[t]) = make_uint2(cvtpk(zr[0], zr[1]), cvtpk(zr[2], zr[3]));
        *(uint2*)(xs + xoff[t]) = make_uint2(cvtpk(t2r[0], t2r[1]), cvtpk(t2r[2], t2r[3]));
      }
    }
  }
  __syncthreads();

  // ---- serial steps k = 1..24 (LDS-only) ----
#pragma unroll 1
  for (int k = 1; k < 25; ++k) {
    const int cur = (k - 1) & 1, nxt = k & 1;

    // x for this step (y-lanes)
    uint2 xq[2];
    xq[0] = make_uint2(0u, 0u);
    xq[1] = make_uint2(0u, 0u);
    if (!isz) {
#pragma unroll
      for (int t = 0; t < 2; ++t)
        xq[t] = *(const uint2*)(xs + k * 4096 + xoff[t]);
    }

    // B fragments from state
    bf16x8 bfr[8];
#pragma unroll
    for (int kk = 0; kk < 8; ++kk)
      bfr[kk] = *(const bf16x8*)(smem + cur * 8192 + roff[kk]);

    f32x4 acc0a = (f32x4){0.f, 0.f, 0.f, 0.f};
    f32x4 acc0b = (f32x4){0.f, 0.f, 0.f, 0.f};
    f32x4 acc1a = (f32x4){0.f, 0.f, 0.f, 0.f};
    f32x4 acc1b = (f32x4){0.f, 0.f, 0.f, 0.f};
#pragma unroll
    for (int kk = 0; kk < 4; ++kk) {
      acc0a = __builtin_amdgcn_mfma_f32_16x16x32_bf16(af[0][kk], bfr[kk], acc0a, 0, 0, 0);
      acc1a = __builtin_amdgcn_mfma_f32_16x16x32_bf16(af[1][kk], bfr[kk], acc1a, 0, 0, 0);
    }
#pragma unroll
    for (int kk = 4; kk < 8; ++kk) {
      acc0b = __builtin_amdgcn_mfma_f32_16x16x32_bf16(af[0][kk], bfr[kk], acc0b, 0, 0, 0);
      acc1b = __builtin_amdgcn_mfma_f32_16x16x32_bf16(af[1][kk], bfr[kk], acc1b, 0, 0, 0);
    }
    f32x4 acc0 = acc0a + acc0b;
    f32x4 acc1 = acc1a + acc1b;

    // epilogue: y -> t1 --shfl--> z; t2 overwrites x-plane k
#pragma unroll
    for (int t = 0; t < 2; ++t) {
      f32x4 acc = t ? acc1 : acc0;
      float xv[4];
      xv[0] = bf2f((short)xq[t].x);
      xv[1] = bf2f((short)(xq[t].x >> 16));
      xv[2] = bf2f((short)xq[t].y);
      xv[3] = bf2f((short)(xq[t].y >> 16));
      float sel[4], tt2[4];
#pragma unroll
      for (int r = 0; r < 4; ++r) {
        float cy = relu_(acc[r]);
        float ynew = xv[r] + cy;                          // valid on y-lanes
        float t1 = relu_(ynew * inv[t][r] + addv[t][r]);  // valid on y-lanes
        float t1s = __shfl_xor(t1, 8);                    // y -> z partner
        float znew = t1s + cy;                            // valid on z-lanes
        tt2[r] = relu_(znew * inv[t][r] + addv[t][r]);
        sel[r] = isz ? znew : ynew;
      }
      *(uint2*)(smem + nxt * 8192 + woff[t]) =
          make_uint2(cvtpk(sel[0], sel[1]), cvtpk(sel[2], sel[3]));
      if (isz)
        *(uint2*)(xs + k * 4096 + xoff[t]) =
            make_uint2(cvtpk(tt2[0], tt2[1]), cvtpk(tt2[2], tt2[3]));
    }
    __syncthreads();
  }

  // ---- parallel post-phase: S[col][dh] = sum_{c,k} A[dh][24-k][c]*t2[k][col][c]
  {
    const int c = tid & 255;
    const int kh = tid >> 8;  // wave-uniform
    float acc[8][3];
#pragma unroll
    for (int nn = 0; nn < 8; ++nn)
#pragma unroll
      for (int dh = 0; dh < 3; ++dh) acc[nn][dh] = 0.f;

    const int kbeg = kh ? 13 : 0, kend = kh ? 25 : 13;
    for (int k = kbeg; k < kend; ++k) {
      float a0 = A[(0 * 25 + 24 - k) * 256 + c];
      float a1 = A[(1 * 25 + 24 - k) * 256 + c];
      float a2 = A[(2 * 25 + 24 - k) * 256 + c];
#pragma unroll
      for (int nn = 0; nn < 8; ++nn) {
        float v = bf2f(*(const short*)(xs + k * 4096 + nn * 512 + 2 * c));
        acc[nn][0] = fmaf(a0, v, acc[nn][0]);
        acc[nn][1] = fmaf(a1, v, acc[nn][1]);
        acc[nn][2] = fmaf(a2, v, acc[nn][2]);
      }
    }
#pragma unroll
    for (int nn = 0; nn < 8; ++nn)
#pragma unroll
      for (int dh = 0; dh < 3; ++dh) {
        float v = acc[nn][dh];
        v += __shfl_xor(v, 1);
        v += __shfl_xor(v, 2);
        v += __shfl_xor(v, 4);
        v += __shfl_xor(v, 8);
        v += __shfl_xor(v, 16);
        v += __shfl_xor(v, 32);
        if (lane == 0) red[wave][nn][dh] = v;
      }
  }
  __syncthreads();
  if (tid < 24) {
    int nn = tid / 3, dh = tid % 3;
    float v = 0.f;
#pragma unroll
    for (int ww = 0; ww < 8; ++ww) v += red[ww][nn][dh];
    S[(size_t)(col0 + nn) * 3 + dh] = v;
  }
}

// P[b][h'] for h' in [0,512)
__global__ __launch_bounds__(256) void k3_outpre(
    const float* __restrict__ S, float* __restrict__ P)
{
  int idx = blockIdx.x * blockDim.x + threadIdx.x;
  if (idx >= 8 * 512) return;
  int b = idx >> 9, h = idx & 511;
  float acc = 0.f;
#pragma unroll
  for (int dh = 0; dh < 3; ++dh) {
    int hh = h + dh - 1;
    if (hh < 0 || hh >= 512) continue;
    float pos = hh * (255.0f / 511.0f);
    int i0 = (int)floorf(pos);
    int i1 = min(i0 + 1, 255);
    float t = pos - (float)i0;
    acc += (1.f - t) * S[(size_t)(b * 256 + i0) * 3 + dh]
         + t * S[(size_t)(b * 256 + i1) * 3 + dh];
  }
  P[idx] = acc;
}

__global__ __launch_bounds__(256) void k4_final(
    const float* __restrict__ P, float* __restrict__ out)
{
  int idx = blockIdx.x * blockDim.x + threadIdx.x;
  if (idx >= 8 * 2048) return;
  int b = idx >> 11, H = idx & 2047;
  const float* Pb = P + b * 512;

  float pos3 = H * (1023.0f / 2047.0f);
  int i3 = (int)floorf(pos3);
  int i3b = min(i3 + 1, 1023);
  float t3 = pos3 - (float)i3;

  float v[2];
#pragma unroll
  for (int q = 0; q < 2; ++q) {
    int i = q ? i3b : i3;
    float pos2 = i * (511.0f / 1023.0f);
    int i2 = (int)floorf(pos2);
    int i2b = min(i2 + 1, 511);
    float t2 = pos2 - (float)i2;
    v[q] = (1.f - t2) * Pb[i2] + t2 * Pb[i2b];
  }
  float val = (1.f - t3) * v[0] + t3 * v[1];
  out[idx] = 1.f / (1.f + expf(-val));
}

extern "C" void kernel_launch(void* const* d_in, const int* in_sizes, int n_in,
                              void* d_out, int out_size, void* d_ws, size_t ws_size,
                              hipStream_t stream) {
  (void)in_sizes; (void)n_in; (void)out_size; (void)ws_size;
  const float* p2r    = (const float*)d_in[0];
  const float* Wmsg   = (const float*)d_in[1];
  const float* gamma  = (const float*)d_in[2];
  const float* beta   = (const float*)d_in[3];
  const float* mean   = (const float*)d_in[4];
  const float* var    = (const float*)d_in[5];
  const float* Wup2   = (const float*)d_in[6];
  const float* Wconv  = (const float*)d_in[7];
  const float* Wconv2 = (const float*)d_in[8];
  float* out = (float*)d_out;

  float* ws = (float*)d_ws;
  size_t off = 0;
  short* WcA = (short*)(ws + off); off += 32768;  // 65536 bf16
  float* Abuf = ws + off; off += 19200;
  float* bnp = ws + off;  off += 512;
  float* S = ws + off;    off += 6144;
  float* P = ws + off;    off += 4096;

  k0_precompute<<<256, 64, 0, stream>>>(Wmsg, gamma, beta, mean, var, Wup2,
                                        Wconv, Wconv2, WcA, Abuf, bnp);
  k2_fused<<<256, 512, 0, stream>>>(p2r, (const short*)WcA, Abuf, bnp, S);
  k3_outpre<<<16, 256, 0, stream>>>(S, P);
  k4_final<<<64, 256, 0, stream>>>(P, out);
}

// Round 5
// 58.036 us; speedup vs baseline: 1.1144x; 1.1144x over previous
//
#include <hip/hip_runtime.h>
#include <math.h>

// Algebraic refactor (verified rounds 1-4, absmax <= 0.0039):
//  y[0]=x[...,0]; y[k]=x[...,k]+relu(Wc@y[k-1])
//  z[0]=f(y[0]);  z[k]=f(y[k])+relu(Wc@z[k-1]),  f(v)=relu(v*inv+add)
//  S[col][dh] = sum_{o,k} A[dh][24-k][o] * t2[k][o][col],  t2[k]=f(z[k])
//  tail: lerp chains + sigmoid (k3,k4)
// Round 5: coalesced staging (1 wave = 1 channel-chunk, lanes contiguous;
//  800B/instr instead of 64 scattered lines) + unified xslab XOR swizzle
//  S(w,rn) = ((2rn+w)&15)<<3 serving staging stores, loop reads/t2 writes,
//  and post-phase reads with <=4-way conflicts.

#define NC 8

typedef __attribute__((ext_vector_type(8))) short bf16x8;
typedef __attribute__((ext_vector_type(4))) float f32x4;

__device__ __forceinline__ float relu_(float v) { return fmaxf(v, 0.f); }

__device__ __forceinline__ short f2bf(float f) {
  union { float f; unsigned u; } v; v.f = f;
  unsigned r = (v.u + 0x7fffu + ((v.u >> 16) & 1u)) >> 16;
  return (short)r;
}
__device__ __forceinline__ float bf2f(short s) {
  union { unsigned u; float f; } v;
  v.u = ((unsigned)(unsigned short)s) << 16;
  return v.f;
}
__device__ __forceinline__ unsigned cvtpk(float lo, float hi) {
  unsigned r;
  asm("v_cvt_pk_bf16_f32 %0, %1, %2" : "=v"(r) : "v"(lo), "v"(hi));
  return r;
}

__global__ __launch_bounds__(64) void k0_precompute(
    const float* __restrict__ Wmsg, const float* __restrict__ gamma,
    const float* __restrict__ beta, const float* __restrict__ mean,
    const float* __restrict__ var, const float* __restrict__ Wup2,
    const float* __restrict__ Wconv, const float* __restrict__ Wconv2,
    short* __restrict__ WcA, float* __restrict__ A, float* __restrict__ bnp)
{
  const int c = blockIdx.x;      // 0..255
  const int lane = threadIdx.x;  // 0..63

  // WcA[o][c] = bf16(Wc[o][c]) (MFMA A operand, row-major [M=o][K=c])
  for (int o = lane; o < 256; o += 64)
    WcA[o * 256 + c] = f2bf(Wmsg[(o * 256 + c) * 9 + 4]);

  const int gtid = c * 64 + lane;
  if (gtid < 256) {
    float inv = gamma[gtid] / sqrtf(var[gtid] + 1e-5f);
    bnp[gtid] = inv;
    bnp[256 + gtid] = beta[gtid] - mean[gtid] * inv;
  }

  float wacc[9];
#pragma unroll
  for (int q = 0; q < 9; ++q) wacc[q] = 0.f;
  for (int o = lane; o < 256; o += 64) {
    float cw = Wconv[o];
    const float* wp = Wup2 + (size_t)(o * 256 + c) * 9;
#pragma unroll
    for (int q = 0; q < 9; ++q) wacc[q] += cw * wp[q];
  }
#pragma unroll
  for (int q = 0; q < 9; ++q) {
    float v = wacc[q];
    v += __shfl_xor(v, 32, 64);
    v += __shfl_xor(v, 16, 64);
    v += __shfl_xor(v, 8, 64);
    v += __shfl_xor(v, 4, 64);
    v += __shfl_xor(v, 2, 64);
    v += __shfl_xor(v, 1, 64);
    wacc[q] = v;
  }
  if (lane == 0) {
    for (int dh = 0; dh < 3; ++dh)
      for (int j = 0; j < 25; ++j) {
        float a = 0.f;
        for (int dw = 0; dw < 3; ++dw) {
          int w = j + 1 - dw;
          if (w >= 0 && w < 25) a += wacc[dh * 3 + dw] * Wconv2[w];
        }
        A[(dh * 25 + j) * 256 + c] = a;
      }
  }
}

// ---- fused MFMA dual-recurrence kernel ----
// Block = 512 threads (8 waves). Wave w owns channels [32w, 32w+32).
// lane n=lane&15: n<8 -> y col n, n>=8 -> z col n-8 (cols = 8 consecutive h).
// xslab layout: [w][rn][c] bf16, swizzled: addr = (w*4096+rn*512+2c) ^ S,
//  S = ((2*rn + w)&15)<<3. Plane w=k is overwritten with t2[k] after use.
__global__ __launch_bounds__(512) void k2_fused(
    const float* __restrict__ X,     // original p2_r [b][c][h][w]
    const short* __restrict__ WcA,   // bf16 [o][c]
    const float* __restrict__ A,     // [(dh*25+w)*256+c]
    const float* __restrict__ bnp,   // inv[256], add[256]
    float* __restrict__ S)           // [col*3+dh]
{
  __shared__ short xslab[25 * 8 * 256];  // 102400B
  __shared__ short yz[2][16 * 256];      // state, swizzled (2x8192B)
  __shared__ float red[8][8][3];
  const int tid = threadIdx.x;
  const int wave = tid >> 6;
  const int lane = tid & 63;
  const int n = lane & 15;
  const int nr = n & 7;
  const int g = lane >> 4;
  const bool isz = (n >= 8);
  const int col0 = blockIdx.x * NC;      // col = b*256+h
  const int b = col0 >> 8, h0 = col0 & 255;
  const int obase = wave * 32;
  char* xs = (char*)xslab;
  char* smem = (char*)yz;

  // ---- stage x-slab: wave handles c in [32*wave, 32*wave+32), lanes 0..49
  //      read 800B contiguous per c (f = 4L..4L+3, f = rn*25+w) ----
  {
    const int L = lane;
    if (L < 50) {
      int base_[4], sx_[4];
#pragma unroll
      for (int e = 0; e < 4; ++e) {
        int f = 4 * L + e;
        int rn = f / 25, w = f - rn * 25;
        base_[e] = w * 4096 + rn * 512;
        sx_[e] = ((2 * rn + w) & 15) << 3;
      }
      const float* src0 = X + ((size_t)(b * 256 + obase) * 256 + h0) * 25 + 4 * L;
#pragma unroll
      for (int half = 0; half < 4; ++half) {
        float4 v[8];
#pragma unroll
        for (int i = 0; i < 8; ++i)
          v[i] = *(const float4*)(src0 + (size_t)(half * 8 + i) * 6400);
#pragma unroll
        for (int i = 0; i < 8; ++i) {
          int c2 = (obase + half * 8 + i) * 2;
          float vv[4] = {v[i].x, v[i].y, v[i].z, v[i].w};
#pragma unroll
          for (int e = 0; e < 4; ++e)
            *(short*)(xs + base_[e] + (c2 ^ sx_[e])) = f2bf(vv[e]);
        }
      }
    }
  }

  // BN params: o = obase + t*16 + g*4 + r
  f32x4 inv[2], addv[2];
#pragma unroll
  for (int t = 0; t < 2; ++t) {
    inv[t] = *(const f32x4*)(bnp + obase + t * 16 + g * 4);
    addv[t] = *(const f32x4*)(bnp + 256 + obase + t * 16 + g * 4);
  }

  // A-operand fragments: rows m = obase + t*16 + n, k = kk*32 + g*8 + i
  bf16x8 af[2][8];
#pragma unroll
  for (int t = 0; t < 2; ++t)
#pragma unroll
    for (int kk = 0; kk < 8; ++kk)
      af[t][kk] = *(const bf16x8*)(WcA + (obase + t * 16 + n) * 256 + kk * 32 + g * 8);

  // LDS byte offsets
  const int swz = nr << 4;
  int woff[2], roff[8], xb[2];
#pragma unroll
  for (int t = 0; t < 2; ++t) {
    woff[t] = n * 512 + (((obase + t * 16 + g * 4) * 2) ^ swz);   // state (swizzled)
    xb[t] = nr * 512 + 2 * (obase + t * 16 + g * 4);              // xslab pre-XOR
  }
#pragma unroll
  for (int kk = 0; kk < 8; ++kk)
    roff[kk] = n * 512 + ((kk * 64 + g * 16) ^ swz);

  __syncthreads();  // slab ready

  // ---- prologue (k = 0): y0 = x0, z0 = f(y0); write state + t2[0] ----
  {
    const int S0 = ((2 * nr) & 15) << 3;
    uint2 xq0[2];
#pragma unroll
    for (int t = 0; t < 2; ++t) xq0[t] = *(const uint2*)(xs + (xb[t] ^ S0));
    if (!isz) {
#pragma unroll
      for (int t = 0; t < 2; ++t)
        *(uint2*)(smem + woff[t]) = xq0[t];  // y0 = x0: raw bf16 copy
    } else {
#pragma unroll
      for (int t = 0; t < 2; ++t) {
        float zr[4], t2r[4];
#pragma unroll
        for (int r = 0; r < 4; ++r) {
          short xbv = (short)(r < 2 ? (r ? (xq0[t].x >> 16) : xq0[t].x)
                                    : (r & 1 ? (xq0[t].y >> 16) : xq0[t].y));
          float x = bf2f(xbv);
          zr[r] = relu_(x * inv[t][r] + addv[t][r]);
          t2r[r] = relu_(zr[r] * inv[t][r] + addv[t][r]);
        }
        *(uint2*)(smem + woff[t]) = make_uint2(cvtpk(zr[0], zr[1]), cvtpk(zr[2], zr[3]));
        *(uint2*)(xs + (xb[t] ^ S0)) =
            make_uint2(cvtpk(t2r[0], t2r[1]), cvtpk(t2r[2], t2r[3]));
      }
    }
  }
  __syncthreads();

  // ---- serial steps k = 1..24 (LDS-only) ----
#pragma unroll 1
  for (int k = 1; k < 25; ++k) {
    const int cur = (k - 1) & 1, nxt = k & 1;
    const int Sk = ((2 * nr + k) & 15) << 3;
    const int kplane = k * 4096;

    // x for this step (y-lanes)
    uint2 xq[2];
    xq[0] = make_uint2(0u, 0u);
    xq[1] = make_uint2(0u, 0u);
    if (!isz) {
#pragma unroll
      for (int t = 0; t < 2; ++t)
        xq[t] = *(const uint2*)(xs + ((xb[t] + kplane) ^ Sk));
    }

    // B fragments from state
    bf16x8 bfr[8];
#pragma unroll
    for (int kk = 0; kk < 8; ++kk)
      bfr[kk] = *(const bf16x8*)(smem + cur * 8192 + roff[kk]);

    f32x4 acc0a = (f32x4){0.f, 0.f, 0.f, 0.f};
    f32x4 acc0b = (f32x4){0.f, 0.f, 0.f, 0.f};
    f32x4 acc1a = (f32x4){0.f, 0.f, 0.f, 0.f};
    f32x4 acc1b = (f32x4){0.f, 0.f, 0.f, 0.f};
#pragma unroll
    for (int kk = 0; kk < 4; ++kk) {
      acc0a = __builtin_amdgcn_mfma_f32_16x16x32_bf16(af[0][kk], bfr[kk], acc0a, 0, 0, 0);
      acc1a = __builtin_amdgcn_mfma_f32_16x16x32_bf16(af[1][kk], bfr[kk], acc1a, 0, 0, 0);
    }
#pragma unroll
    for (int kk = 4; kk < 8; ++kk) {
      acc0b = __builtin_amdgcn_mfma_f32_16x16x32_bf16(af[0][kk], bfr[kk], acc0b, 0, 0, 0);
      acc1b = __builtin_amdgcn_mfma_f32_16x16x32_bf16(af[1][kk], bfr[kk], acc1b, 0, 0, 0);
    }
    f32x4 acc0 = acc0a + acc0b;
    f32x4 acc1 = acc1a + acc1b;

    // epilogue: y -> t1 --shfl--> z; t2 overwrites x-plane k
#pragma unroll
    for (int t = 0; t < 2; ++t) {
      f32x4 acc = t ? acc1 : acc0;
      float xv[4];
      xv[0] = bf2f((short)xq[t].x);
      xv[1] = bf2f((short)(xq[t].x >> 16));
      xv[2] = bf2f((short)xq[t].y);
      xv[3] = bf2f((short)(xq[t].y >> 16));
      float sel[4], tt2[4];
#pragma unroll
      for (int r = 0; r < 4; ++r) {
        float cy = relu_(acc[r]);
        float ynew = xv[r] + cy;                          // valid on y-lanes
        float t1 = relu_(ynew * inv[t][r] + addv[t][r]);  // valid on y-lanes
        float t1s = __shfl_xor(t1, 8);                    // y -> z partner
        float znew = t1s + cy;                            // valid on z-lanes
        tt2[r] = relu_(znew * inv[t][r] + addv[t][r]);
        sel[r] = isz ? znew : ynew;
      }
      *(uint2*)(smem + nxt * 8192 + woff[t]) =
          make_uint2(cvtpk(sel[0], sel[1]), cvtpk(sel[2], sel[3]));
      if (isz)
        *(uint2*)(xs + ((xb[t] + kplane) ^ Sk)) =
            make_uint2(cvtpk(tt2[0], tt2[1]), cvtpk(tt2[2], tt2[3]));
    }
    __syncthreads();
  }

  // ---- parallel post-phase: S[col][dh] = sum_{c,k} A[dh][24-k][c]*t2[k][col][c]
  {
    const int c = tid & 255;
    const int kh = tid >> 8;  // wave-uniform
    float acc[8][3];
#pragma unroll
    for (int nn = 0; nn < 8; ++nn)
#pragma unroll
      for (int dh = 0; dh < 3; ++dh) acc[nn][dh] = 0.f;

    const int kbeg = kh ? 13 : 0, kend = kh ? 25 : 13;
    for (int k = kbeg; k < kend; ++k) {
      float a0 = A[(0 * 25 + 24 - k) * 256 + c];
      float a1 = A[(1 * 25 + 24 - k) * 256 + c];
      float a2 = A[(2 * 25 + 24 - k) * 256 + c];
#pragma unroll
      for (int nn = 0; nn < 8; ++nn) {
        int Sp = ((2 * nn + k) & 15) << 3;
        float v = bf2f(*(const short*)(xs + ((k * 4096 + nn * 512 + 2 * c) ^ Sp)));
        acc[nn][0] = fmaf(a0, v, acc[nn][0]);
        acc[nn][1] = fmaf(a1, v, acc[nn][1]);
        acc[nn][2] = fmaf(a2, v, acc[nn][2]);
      }
    }
#pragma unroll
    for (int nn = 0; nn < 8; ++nn)
#pragma unroll
      for (int dh = 0; dh < 3; ++dh) {
        float v = acc[nn][dh];
        v += __shfl_xor(v, 1);
        v += __shfl_xor(v, 2);
        v += __shfl_xor(v, 4);
        v += __shfl_xor(v, 8);
        v += __shfl_xor(v, 16);
        v += __shfl_xor(v, 32);
        if (lane == 0) red[wave][nn][dh] = v;
      }
  }
  __syncthreads();
  if (tid < 24) {
    int nn = tid / 3, dh = tid % 3;
    float v = 0.f;
#pragma unroll
    for (int ww = 0; ww < 8; ++ww) v += red[ww][nn][dh];
    S[(size_t)(col0 + nn) * 3 + dh] = v;
  }
}

// P[b][h'] for h' in [0,512)
__global__ __launch_bounds__(256) void k3_outpre(
    const float* __restrict__ S, float* __restrict__ P)
{
  int idx = blockIdx.x * blockDim.x + threadIdx.x;
  if (idx >= 8 * 512) return;
  int b = idx >> 9, h = idx & 511;
  float acc = 0.f;
#pragma unroll
  for (int dh = 0; dh < 3; ++dh) {
    int hh = h + dh - 1;
    if (hh < 0 || hh >= 512) continue;
    float pos = hh * (255.0f / 511.0f);
    int i0 = (int)floorf(pos);
    int i1 = min(i0 + 1, 255);
    float t = pos - (float)i0;
    acc += (1.f - t) * S[(size_t)(b * 256 + i0) * 3 + dh]
         + t * S[(size_t)(b * 256 + i1) * 3 + dh];
  }
  P[idx] = acc;
}

__global__ __launch_bounds__(256) void k4_final(
    const float* __restrict__ P, float* __restrict__ out)
{
  int idx = blockIdx.x * blockDim.x + threadIdx.x;
  if (idx >= 8 * 2048) return;
  int b = idx >> 11, H = idx & 2047;
  const float* Pb = P + b * 512;

  float pos3 = H * (1023.0f / 2047.0f);
  int i3 = (int)floorf(pos3);
  int i3b = min(i3 + 1, 1023);
  float t3 = pos3 - (float)i3;

  float v[2];
#pragma unroll
  for (int q = 0; q < 2; ++q) {
    int i = q ? i3b : i3;
    float pos2 = i * (511.0f / 1023.0f);
    int i2 = (int)floorf(pos2);
    int i2b = min(i2 + 1, 511);
    float t2 = pos2 - (float)i2;
    v[q] = (1.f - t2) * Pb[i2] + t2 * Pb[i2b];
  }
  float val = (1.f - t3) * v[0] + t3 * v[1];
  out[idx] = 1.f / (1.f + expf(-val));
}

extern "C" void kernel_launch(void* const* d_in, const int* in_sizes, int n_in,
                              void* d_out, int out_size, void* d_ws, size_t ws_size,
                              hipStream_t stream) {
  (void)in_sizes; (void)n_in; (void)out_size; (void)ws_size;
  const float* p2r    = (const float*)d_in[0];
  const float* Wmsg   = (const float*)d_in[1];
  const float* gamma  = (const float*)d_in[2];
  const float* beta   = (const float*)d_in[3];
  const float* mean   = (const float*)d_in[4];
  const float* var    = (const float*)d_in[5];
  const float* Wup2   = (const float*)d_in[6];
  const float* Wconv  = (const float*)d_in[7];
  const float* Wconv2 = (const float*)d_in[8];
  float* out = (float*)d_out;

  float* ws = (float*)d_ws;
  size_t off = 0;
  short* WcA = (short*)(ws + off); off += 32768;  // 65536 bf16
  float* Abuf = ws + off; off += 19200;
  float* bnp = ws + off;  off += 512;
  float* S = ws + off;    off += 6144;
  float* P = ws + off;    off += 4096;

  k0_precompute<<<256, 64, 0, stream>>>(Wmsg, gamma, beta, mean, var, Wup2,
                                        Wconv, Wconv2, WcA, Abuf, bnp);
  k2_fused<<<256, 512, 0, stream>>>(p2r, (const short*)WcA, Abuf, bnp, S);
  k3_outpre<<<16, 256, 0, stream>>>(S, P);
  k4_final<<<64, 256, 0, stream>>>(P, out);
}